// Round 12
// baseline (152.304 us; speedup 1.0000x reference)
//
#include <hip/hip_runtime.h>
#include <math.h>

#define L_SEQ 16384
#define H_DIM 1024
#define P_DIM 512
#define N2P   1024
#define KDIM  1024
#define NKT   16     // KDIM / 64
#define CHUNK 64
#define NCHUNK 256   // L_SEQ / CHUNK

typedef __attribute__((ext_vector_type(8))) short short8;
typedef __attribute__((ext_vector_type(4))) float f32x4;

__device__ __forceinline__ unsigned short f2bf(float f){
    unsigned int u = __float_as_uint(f);
    u = (u + 0x7FFFu + ((u >> 16) & 1u)) >> 16;
    return (unsigned short)u;
}
__device__ __forceinline__ float bf2f(unsigned int lo16){
    return __uint_as_float(lo16 << 16);
}

// ---------------- prep ----------------
__global__ void k_prep_lambda(const float* __restrict__ lre, const float* __restrict__ lim,
                              const float* __restrict__ lstep,
                              float* __restrict__ lam, float* __restrict__ coef,
                              float* __restrict__ lpow)
{
    int p = threadIdx.x;
    double step = exp((double)lstep[p]);
    double dr = (double)lre[p], di = (double)lim[p];
    double ar = dr*step, ai = di*step;
    double er = exp(ar);
    double lbr = er*cos(ai), lbi = er*sin(ai);
    lam[2*p] = (float)lbr; lam[2*p+1] = (float)lbi;
    double nr = lbr - 1.0, ni = lbi;
    double d2 = dr*dr + di*di;
    coef[2*p]   = (float)((nr*dr + ni*di)/d2);
    coef[2*p+1] = (float)((ni*dr - nr*di)/d2);
    double xr = lbr, xi = lbi;
    #pragma unroll
    for (int s=0;s<6;s++){ double t = xr*xr - xi*xi; xi = 2.0*xr*xi; xr = t; } // ^64
    lpow[2*p] = (float)xr; lpow[2*p+1] = (float)xi;
}

__global__ __launch_bounds__(256)
void k_prep_bc(const float* __restrict__ B, const float* __restrict__ C,
               const float* __restrict__ coef,
               unsigned short* __restrict__ BB, unsigned short* __restrict__ CC)
{
    int bid = blockIdx.x;
    if (bid < 2048){
        int i = bid*256 + threadIdx.x;   // i = p*H + h
        int p = i >> 10, h = i & 1023;
        float br = B[2*i], bi = B[2*i+1];
        float cr = coef[2*p], ci = coef[2*p+1];
        BB[(size_t)(2*p)*H_DIM + h]   = f2bf(cr*br - ci*bi);
        BB[(size_t)(2*p+1)*H_DIM + h] = f2bf(cr*bi + ci*br);
    } else {
        int i = (bid-2048)*256 + threadIdx.x;   // i = h*P + p
        int h = i >> 9, p = i & 511;
        float cr = C[2*i], ci = C[2*i+1];
        CC[(size_t)h*N2P + 2*p]     = f2bf(2.f*cr);
        CC[(size_t)h*N2P + 2*p + 1] = f2bf(-2.f*ci);
    }
}

// ---------------- GEMM: 128x128, BK=64, 4 waves, 2 resident + 2 sequential/CU ----
// CAST=1 (gemm1): A read as fp32 (u) and cast to bf16 during reg-staging (k_cast
//   fused away); B staged via global_load_lds. Output bf16 to Cb.
// CAST=0 (gemm2): A (xs16) and B both via global_load_lds. Output fp32 to Cf with
//   += Dv[col] * u_fp32[idx] epilogue.
// Race-free depth-1 dbuf: at iteration kt the start-of-iteration barrier (end of
//   kt-1's __syncthreads) proves all waves finished reading parity (kt+1)&1 at
//   kt-1 -> staging kt+1 there is safe. __syncthreads at iter end performs the
//   REQUIRED vmcnt(0)/lgkm(0) drain (stages+ds_writes landed) + barrier.
// Swizzle (both sides, 0 conflicts measured R4-R11): phys 16B-chunk = logical ^ (row&7).
template<int CAST>
__global__ __launch_bounds__(256, 2)
void gemm128(const unsigned short* __restrict__ A16, const float* __restrict__ A32,
             const unsigned short* __restrict__ Bm,
             float* __restrict__ Cf, unsigned short* __restrict__ Cb,
             const float* __restrict__ Dv, const float* __restrict__ U32)
{
    __shared__ char lds[65536];
    const int tid  = threadIdx.x;
    const int lane = tid & 63;
    const int wid  = tid >> 6;
    const int wm = wid >> 1, wn = wid & 1;            // 2(M) x 2(N), wave = 64x64
    const int wg = ((int)blockIdx.x & 7) * 128 + ((int)blockIdx.x >> 3);  // XCD swizzle
    const int tm = wg >> 3, tn = wg & 7;
    const int lr = lane & 15;

    // staging geometry: thread covers LDS bytes tid*16 (+4096 per g), i.e.
    // row g*32 + (tid>>3), phys chunk tid&7; logical source chunk = (tid&7)^(row&7).
    const int srow = tid >> 3;                               // 0..31
    const int sch  = (tid & 7) ^ ((tid >> 3) & 7);           // logical 16B chunk
    const int scol = sch << 3;                               // ushort units
    // reads: row R; byte = R*128 + ((g|4ks)^(R&7))*16, R&7 == lr&7
    const int kc0 = (((lane >> 4)      ^ (lr & 7)) << 4);
    const int kc1 = ((((lane >> 4) | 4) ^ (lr & 7)) << 4);
    const int aOff = (wm*64 + lr)*128;                       // + m*2048 + kc
    const int bOff = 16384 + (wn*64 + lr)*128;               // + n*2048 + kc

#define GLOAD(SRC, DST) __builtin_amdgcn_global_load_lds( \
        (const __attribute__((address_space(1))) void*)(SRC), \
        (__attribute__((address_space(3))) void*)(DST), 16, 0, 0)
#define RD(OFF) (*(const short8*)(lds + (OFF)))
#define MFMA(a,b,c) __builtin_amdgcn_mfma_f32_16x16x32_bf16(a,b,c,0,0,0)

    // B stage (both modes): 4 gload_lds
    auto stage_b = [&](int kt_){
        char* d_ = lds + ((kt_&1)<<15) + 16384 + tid*16;
        const unsigned short* sb = Bm + (size_t)(tn*128 + srow)*KDIM + (size_t)kt_*64 + scol;
        GLOAD(sb,                    d_);
        GLOAD(sb + (size_t)32*KDIM,  d_ + 4096);
        GLOAD(sb + (size_t)64*KDIM,  d_ + 8192);
        GLOAD(sb + (size_t)96*KDIM,  d_ + 12288);
    };
    // A stage, bf16 source: 4 gload_lds
    auto stage_a16 = [&](int kt_){
        char* d_ = lds + ((kt_&1)<<15) + tid*16;
        const unsigned short* sa = A16 + (size_t)(tm*128 + srow)*KDIM + (size_t)kt_*64 + scol;
        GLOAD(sa,                    d_);
        GLOAD(sa + (size_t)32*KDIM,  d_ + 4096);
        GLOAD(sa + (size_t)64*KDIM,  d_ + 8192);
        GLOAD(sa + (size_t)96*KDIM,  d_ + 12288);
    };

    f32x4 acc[4][4];
    #pragma unroll
    for (int m=0;m<4;m++)
        #pragma unroll
        for (int n=0;n<4;n++) acc[m][n] = (f32x4){0.f,0.f,0.f,0.f};

    // fp32 A staging (CAST mode): load 8 floats per g, cast, one ds_write_b128 per g
    float4 av[4][2];
    auto load_a32 = [&](int kt_){
        #pragma unroll
        for (int g=0; g<4; ++g){
            const float* sa = A32 + (size_t)(tm*128 + g*32 + srow)*KDIM + (size_t)kt_*64 + scol;
            av[g][0] = *reinterpret_cast<const float4*>(sa);
            av[g][1] = *reinterpret_cast<const float4*>(sa + 4);
        }
    };
    auto write_a32 = [&](int kt_){
        #pragma unroll
        for (int g=0; g<4; ++g){
            union { short8 v; unsigned short s[8]; } r;
            r.s[0]=f2bf(av[g][0].x); r.s[1]=f2bf(av[g][0].y);
            r.s[2]=f2bf(av[g][0].z); r.s[3]=f2bf(av[g][0].w);
            r.s[4]=f2bf(av[g][1].x); r.s[5]=f2bf(av[g][1].y);
            r.s[6]=f2bf(av[g][1].z); r.s[7]=f2bf(av[g][1].w);
            *reinterpret_cast<short8*>(lds + ((kt_&1)<<15) + g*4096 + tid*16) = r.v;
        }
    };

    // prologue: stage KT0 into parity 0
    if (CAST){ load_a32(0); write_a32(0); } else { stage_a16(0); }
    stage_b(0);
    __syncthreads();

    for (int kt = 0; kt < NKT; ++kt) {
        const int sb = (kt & 1) << 15;
        const int tN = (kt + 1) & (NKT - 1);   // kt=15 -> 0: parity-0 slot fully read at kt=14
        // ---- stage kt+1 into the other parity (race-free: that slot's readers
        // finished at kt-1, proven by the barrier that started this iteration)
        if (CAST) load_a32(tN); else stage_a16(tN);
        stage_b(tN);

        // ---- compute kt from parity kt&1 (plain derefs, compiler-scheduled)
        short8 a0[4], b0[4], a1v[4], b1v[4];
        #pragma unroll
        for (int m=0;m<4;m++) a0[m]  = RD(sb + aOff + m*2048 + kc0);
        #pragma unroll
        for (int n=0;n<4;n++) b0[n]  = RD(sb + bOff + n*2048 + kc0);
        #pragma unroll
        for (int m=0;m<4;m++) a1v[m] = RD(sb + aOff + m*2048 + kc1);
        #pragma unroll
        for (int n=0;n<4;n++) b1v[n] = RD(sb + bOff + n*2048 + kc1);
        #pragma unroll
        for (int m=0;m<4;m++)
            #pragma unroll
            for (int n=0;n<4;n++) acc[m][n] = MFMA(a0[m], b0[n], acc[m][n]);
        #pragma unroll
        for (int m=0;m<4;m++)
            #pragma unroll
            for (int n=0;n<4;n++) acc[m][n] = MFMA(a1v[m], b1v[n], acc[m][n]);

        // ---- complete A stage for CAST mode (compiler waits on av loads here)
        if (CAST) write_a32(tN);
        // required drain: vmcnt(0) (stages landed) + lgkm(0) (ds_writes done) + barrier
        __syncthreads();
    }

    const int orow0 = tm*128 + wm*64 + (lane>>4)*4;
    const int ocol0 = tn*128 + wn*64 + lr;
    #pragma unroll
    for (int m=0;m<4;m++){
        #pragma unroll
        for (int n=0;n<4;n++){
            int row = orow0 + m*16, col = ocol0 + n*16;
            #pragma unroll
            for (int j=0;j<4;j++){
                size_t idx = (size_t)(row + j)*N2P + col;
                if (CAST) Cb[idx] = f2bf(acc[m][n][j]);
                else      Cf[idx] = acc[m][n][j] + Dv[col]*U32[idx];
            }
        }
    }
#undef GLOAD
#undef RD
#undef MFMA
}

// ---------------- scan phase 1: per-(chunk, p) aggregate (Bu in bf16 pairs) -------
__global__ __launch_bounds__(512)
void k_agg(const unsigned int* __restrict__ Bu, const float* __restrict__ lam,
           float* __restrict__ agg)
{
    int p = threadIdx.x, c = blockIdx.x;
    float lrr = lam[2*p], lii = lam[2*p+1];
    float xr = 0.f, xi = 0.f;
    const unsigned int* b2 = Bu + (size_t)c*CHUNK*512 + p;
    #pragma unroll 4
    for (int t=0;t<CHUNK;t++){
        unsigned int b = b2[(size_t)t*512];
        float br = __uint_as_float(b << 16);
        float bi = __uint_as_float(b & 0xffff0000u);
        float tr = lrr*xr - lii*xi + br;
        xi = lrr*xi + lii*xr + bi;
        xr = tr;
    }
    agg[((size_t)c*P_DIM + p)*2]     = xr;
    agg[((size_t)c*P_DIM + p)*2 + 1] = xi;
}

// ---------------- scan phase 2: Kogge-Stone over chunks ---------------------
__global__ __launch_bounds__(256)
void k_scan(const float* __restrict__ agg, const float* __restrict__ lpow,
            float* __restrict__ xinit)
{
    __shared__ float sr[NCHUNK], si[NCHUNK];
    int c = threadIdx.x, p = blockIdx.x;
    float xr = agg[((size_t)c*P_DIM + p)*2];
    float xi = agg[((size_t)c*P_DIM + p)*2 + 1];
    sr[c] = xr; si[c] = xi;
    float wr = lpow[2*p], wi = lpow[2*p+1];
    for (int s=1; s<NCHUNK; s<<=1){
        __syncthreads();
        float ur = 0.f, ui = 0.f;
        if (c >= s){ ur = sr[c-s]; ui = si[c-s]; }
        __syncthreads();
        xr += wr*ur - wi*ui;
        xi += wr*ui + wi*ur;
        sr[c] = xr; si[c] = xi;
        float t = wr*wr - wi*wi; wi = 2.f*wr*wi; wr = t;
    }
    __syncthreads();
    float er = 0.f, ei = 0.f;
    if (c > 0){ er = sr[c-1]; ei = si[c-1]; }
    xinit[((size_t)c*P_DIM + p)*2]     = er;
    xinit[((size_t)c*P_DIM + p)*2 + 1] = ei;
}

// ---------------- scan phase 3: apply + emit bf16 pairs ----------------------
__global__ __launch_bounds__(512)
void k_apply(const unsigned int* __restrict__ Bu, const float* __restrict__ lam,
             const float* __restrict__ xinit, unsigned int* __restrict__ xs)
{
    int p = threadIdx.x, c = blockIdx.x;
    float lrr = lam[2*p], lii = lam[2*p+1];
    float xr = xinit[((size_t)c*P_DIM + p)*2];
    float xi = xinit[((size_t)c*P_DIM + p)*2 + 1];
    const unsigned int* b2 = Bu + (size_t)c*CHUNK*512 + p;
    unsigned int* o = xs + (size_t)c*CHUNK*512 + p;
    #pragma unroll 4
    for (int t=0;t<CHUNK;t++){
        unsigned int b = b2[(size_t)t*512];
        float br = __uint_as_float(b << 16);
        float bi = __uint_as_float(b & 0xffff0000u);
        float tr = lrr*xr - lii*xi + br;
        xi = lrr*xi + lii*xr + bi;
        xr = tr;
        o[(size_t)t*512] = (unsigned int)f2bf(xr) | ((unsigned int)f2bf(xi) << 16);
    }
}

extern "C" void kernel_launch(void* const* d_in, const int* in_sizes, int n_in,
                              void* d_out, int out_size, void* d_ws, size_t ws_size,
                              hipStream_t stream)
{
    const float* u   = (const float*)d_in[0];
    const float* lre = (const float*)d_in[1];
    const float* lim = (const float*)d_in[2];
    const float* B   = (const float*)d_in[3];
    const float* C   = (const float*)d_in[4];
    const float* D   = (const float*)d_in[5];
    const float* ls  = (const float*)d_in[6];
    float* out = (float*)d_out;

    char* w = (char*)d_ws;
    unsigned short* xs16 = (unsigned short*)(w + 0);          // 32 MiB
    unsigned short* Bu16 = (unsigned short*)(w + 33554432);   // 32 MiB
    unsigned short* BB   = (unsigned short*)(w + 67108864);   // 2 MiB
    unsigned short* CC   = (unsigned short*)(w + 69206016);   // 2 MiB
    float* lam   = (float*)(w + 71303168);
    float* coef  = (float*)(w + 71307264);
    float* lpow  = (float*)(w + 71311360);
    float* agg   = (float*)(w + 71315456);                    // 1 MiB
    float* xinit = (float*)(w + 72364032);                    // 1 MiB

    k_prep_lambda<<<1, P_DIM, 0, stream>>>(lre, lim, ls, lam, coef, lpow);
    k_prep_bc<<<4096, 256, 0, stream>>>(B, C, coef, BB, CC);

    // gemm1: Bu16 = bf16( u @ BB^T ), cast of u fused into A-staging
    gemm128<1><<<1024, 256, 0, stream>>>(nullptr, u, BB, nullptr, Bu16, nullptr, nullptr);

    k_agg<<<NCHUNK, P_DIM, 0, stream>>>((const unsigned int*)Bu16, lam, agg);
    k_scan<<<P_DIM, NCHUNK, 0, stream>>>(agg, lpow, xinit);
    k_apply<<<NCHUNK, P_DIM, 0, stream>>>((const unsigned int*)Bu16, lam, xinit,
                                          (unsigned int*)xs16);

    // gemm2: out = xs16 @ CC^T + D*u   (D*u from fp32 u in epilogue)
    gemm128<0><<<1024, 256, 0, stream>>>(xs16, nullptr, CC, out, nullptr, D, u);
}